// Round 8
// baseline (261.576 us; speedup 1.0000x reference)
//
#include <hip/hip_runtime.h>

#define THREADS 256
#define CHUNK 4096        // edges per binA block
#define BCAP  16384       // per-bucket edge capacity (mean 8163; fixed input, huge slack)
#define CCAP  (BCAP+256)  // csr region capacity (edges + self entries)

// mega1: blocks [0,nbinA) bin edges into bucket regions (2KB LDS);
//        blocks [nbinA,..) compute h = x @ W1 unscaled (16KB LDS, 2 rows/thread).
__global__ __launch_bounds__(256)
void k_mega1(const int* __restrict__ src, const int* __restrict__ dst, int E,
             int* __restrict__ cursor, unsigned int* __restrict__ binned,
             const float* __restrict__ x, const float* __restrict__ W,
             float* __restrict__ h, int N, int nbinA) {
    __shared__ int cnt[256];
    __shared__ int gbs[256];
    __shared__ float Wsh[4096];
    int tid = threadIdx.x;
    if ((int)blockIdx.x < nbinA) {
        // ---------- binA: rank + reserve + direct scatter into owned runs ----------
        cnt[tid] = 0;
        __syncthreads();
        int base = blockIdx.x * CHUNK;
        unsigned int pk[16];
        int rk[16];
        unsigned int mask = 0;
        #pragma unroll
        for (int i = 0; i < 4; ++i) {
            int e = base + i * 1024 + tid * 4;
            if (e + 3 < E) {
                int4 d4 = *reinterpret_cast<const int4*>(dst + e);
                int4 s4 = *reinterpret_cast<const int4*>(src + e);
                pk[i*4+0] = ((unsigned)d4.x << 16) | (unsigned)s4.x; rk[i*4+0] = atomicAdd(&cnt[d4.x >> 8], 1);
                pk[i*4+1] = ((unsigned)d4.y << 16) | (unsigned)s4.y; rk[i*4+1] = atomicAdd(&cnt[d4.y >> 8], 1);
                pk[i*4+2] = ((unsigned)d4.z << 16) | (unsigned)s4.z; rk[i*4+2] = atomicAdd(&cnt[d4.z >> 8], 1);
                pk[i*4+3] = ((unsigned)d4.w << 16) | (unsigned)s4.w; rk[i*4+3] = atomicAdd(&cnt[d4.w >> 8], 1);
                mask |= 0xFu << (i * 4);
            } else {
                for (int j = 0; j < 4; ++j) {
                    int k = e + j;
                    if (k < E) {
                        int d = dst[k], s = src[k];
                        pk[i*4+j] = ((unsigned)d << 16) | (unsigned)s;
                        rk[i*4+j] = atomicAdd(&cnt[d >> 8], 1);
                        mask |= 1u << (i * 4 + j);
                    }
                }
            }
        }
        __syncthreads();
        int c = cnt[tid];
        gbs[tid] = c ? atomicAdd(&cursor[tid], c) : 0;
        __syncthreads();
        #pragma unroll
        for (int i = 0; i < 16; ++i) {
            if (mask & (1u << i)) {
                int b = pk[i] >> 24;
                binned[(size_t)b * BCAP + gbs[b] + rk[i]] = pk[i];
            }
        }
    } else {
        // ---------- gemm1: 512 rows/block, 2 rows/thread, W broadcast from LDS ----------
        int row0 = ((int)blockIdx.x - nbinA) * 512;
        for (int j = tid; j < 1024; j += 256)
            reinterpret_cast<float4*>(Wsh)[j] = reinterpret_cast<const float4*>(W)[j];
        __syncthreads();
        int rowA = row0 + tid;
        int rowB = row0 + 256 + tid;
        bool vA = rowA < N, vB = rowB < N;
        const float4* xA = reinterpret_cast<const float4*>(x + (size_t)rowA * 128);
        const float4* xB = reinterpret_cast<const float4*>(x + (size_t)rowB * 128);
        float accA[32], accB[32];
        #pragma unroll
        for (int q = 0; q < 32; ++q) { accA[q] = 0.f; accB[q] = 0.f; }
        const float4 z4 = make_float4(0.f, 0.f, 0.f, 0.f);
        for (int kc = 0; kc < 128; kc += 16) {
            float4 fa[4], fb[4];
            #pragma unroll
            for (int j2 = 0; j2 < 4; ++j2) {
                fa[j2] = vA ? xA[(kc >> 2) + j2] : z4;
                fb[j2] = vB ? xB[(kc >> 2) + j2] : z4;
            }
            const float* pa = reinterpret_cast<const float*>(fa);
            const float* pb = reinterpret_cast<const float*>(fb);
            #pragma unroll
            for (int k = 0; k < 16; ++k) {
                float va = pa[k], vb = pb[k];
                const float4* wr = reinterpret_cast<const float4*>(Wsh + (kc + k) * 32);
                #pragma unroll
                for (int q = 0; q < 8; ++q) {
                    float4 w = wr[q];
                    accA[q*4+0] += va * w.x; accA[q*4+1] += va * w.y;
                    accA[q*4+2] += va * w.z; accA[q*4+3] += va * w.w;
                    accB[q*4+0] += vb * w.x; accB[q*4+1] += vb * w.y;
                    accB[q*4+2] += vb * w.z; accB[q*4+3] += vb * w.w;
                }
            }
        }
        if (vA) {
            float4* o = reinterpret_cast<float4*>(h + (size_t)rowA * 32);
            #pragma unroll
            for (int q = 0; q < 8; ++q)
                o[q] = make_float4(accA[q*4], accA[q*4+1], accA[q*4+2], accA[q*4+3]);
        }
        if (vB) {
            float4* o = reinterpret_cast<float4*>(h + (size_t)rowB * 32);
            #pragma unroll
            for (int q = 0; q < 8; ++q)
                o[q] = make_float4(accB[q*4], accB[q*4+1], accB[q*4+2], accB[q*4+3]);
        }
    }
}

// binB: per-bucket node counts -> rowbeg/rowend/dinv/csr (self entry first),
// then scale h rows by dinv in place (hp = h * dinv[row]).
__global__ __launch_bounds__(256)
void k_binB(const unsigned int* __restrict__ binned, const int* __restrict__ cursor,
            int* __restrict__ rowbeg, int* __restrict__ rowend, float* __restrict__ dinvg,
            unsigned short* __restrict__ csr, float* __restrict__ h, int N) {
    __shared__ int cnt[256];
    __shared__ int sc[256];
    __shared__ int lcur[256];
    __shared__ float dv[256];
    int tid = threadIdx.x;
    int b = blockIdx.x;
    size_t ebase = (size_t)b * BCAP;
    int ne = cursor[b];
    cnt[tid] = 0;
    __syncthreads();
    for (int i = tid; i < ne; i += 256)
        atomicAdd(&cnt[(binned[ebase + i] >> 16) & 255], 1);
    __syncthreads();
    int myc = cnt[tid];
    sc[tid] = myc;
    __syncthreads();
    for (int off = 1; off < 256; off <<= 1) {
        int v = (tid >= off) ? sc[tid - off] : 0;
        __syncthreads();
        sc[tid] += v;
        __syncthreads();
    }
    int excl = sc[tid] - myc;
    int node = (b << 8) + tid;
    int cbase = b * CCAP;
    int rb = cbase + excl + tid;
    float di = rsqrtf((float)(myc + 1));
    dv[tid] = di;
    if (node < N) {
        rowbeg[node] = rb;
        rowend[node] = rb + 1 + myc;
        dinvg[node] = di;
        csr[rb] = (unsigned short)node;   // self entry first
    }
    lcur[tid] = excl + tid + 1;
    __syncthreads();
    for (int i = tid; i < ne; i += 256) {
        unsigned int v = binned[ebase + i];
        int nl = (v >> 16) & 255;
        int p = atomicAdd(&lcur[nl], 1);
        csr[cbase + p] = (unsigned short)(v & 0xFFFFu);
    }
    __syncthreads();
    float4* h4 = reinterpret_cast<float4*>(h);
    size_t h4base = (size_t)(b << 8) * 8;
    for (int j = tid; j < 2048; j += 256) {
        int nl = j >> 3;
        if (((b << 8) + nl) < N) {
            float4 v = h4[h4base + j];
            float d = dv[nl];
            v.x *= d; v.y *= d; v.z *= d; v.w *= d;
            h4[h4base + j] = v;
        }
    }
}

// agg layer1 + bias + relu + gemm2 + dinv pre-scale: hp2 = relu(agg(hp1)*dinv + b1) @ W2 * dinv
// 1 wave per node; lane = j*8+q for the gather; epilogue lane<32 -> output col.
__global__ __launch_bounds__(THREADS)
void k_aggmm1(const float* __restrict__ hp, const int* __restrict__ rowbeg,
              const int* __restrict__ rowend, const unsigned short* __restrict__ csr,
              const float* __restrict__ dinv, const float* __restrict__ b1,
              const float* __restrict__ W2, float* __restrict__ hp2, int N) {
    __shared__ float W2s[1024];
    __shared__ float b1s[32];
    int tid = threadIdx.x;
    for (int j = tid; j < 256; j += 256)
        reinterpret_cast<float4*>(W2s)[j] = reinterpret_cast<const float4*>(W2)[j];
    if (tid < 32) b1s[tid] = b1[tid];
    __syncthreads();
    int lane = tid & 63;
    int node = blockIdx.x * 4 + (tid >> 6);
    if (node >= N) return;
    int j = lane >> 3, q = lane & 7;
    int beg = rowbeg[node];
    int end = rowend[node];
    float4 acc = make_float4(0.f, 0.f, 0.f, 0.f);
    for (int base = beg; base < end; base += 64) {
        int idx = base + lane;
        int cv = (idx < end) ? (int)csr[idx] : 0;
        int nin = end - base; if (nin > 64) nin = 64;
        for (int c = 0; c < nin; c += 8) {
            int s = __shfl(cv, c + j, 64);
            if (c + j < nin) {
                const float4 v = *reinterpret_cast<const float4*>(hp + (size_t)s * 32 + q * 4);
                acc.x += v.x; acc.y += v.y; acc.z += v.z; acc.w += v.w;
            }
        }
    }
    #pragma unroll
    for (int d = 8; d < 64; d <<= 1) {
        acc.x += __shfl_xor(acc.x, d, 64);
        acc.y += __shfl_xor(acc.y, d, 64);
        acc.z += __shfl_xor(acc.z, d, 64);
        acc.w += __shfl_xor(acc.w, d, 64);
    }
    float dd = dinv[node];
    int cp = lane & 31;
    float o = 0.f;
    #pragma unroll
    for (int qq = 0; qq < 8; ++qq) {
        float t0 = __shfl(acc.x, qq, 64);
        float t1 = __shfl(acc.y, qq, 64);
        float t2 = __shfl(acc.z, qq, 64);
        float t3 = __shfl(acc.w, qq, 64);
        float y0 = fmaxf(t0 * dd + b1s[qq*4+0], 0.f);
        float y1 = fmaxf(t1 * dd + b1s[qq*4+1], 0.f);
        float y2 = fmaxf(t2 * dd + b1s[qq*4+2], 0.f);
        float y3 = fmaxf(t3 * dd + b1s[qq*4+3], 0.f);
        o += y0 * W2s[(qq*4+0)*32 + cp];
        o += y1 * W2s[(qq*4+1)*32 + cp];
        o += y2 * W2s[(qq*4+2)*32 + cp];
        o += y3 * W2s[(qq*4+3)*32 + cp];
    }
    if (lane < 32) hp2[(size_t)node * 32 + cp] = o * dd;
}

// agg layer2 + bias + relu + head: out = relu(agg(hp2)*dinv + b2) @ Wout + bout
__global__ __launch_bounds__(THREADS)
void k_aggout(const float* __restrict__ hp, const int* __restrict__ rowbeg,
              const int* __restrict__ rowend, const unsigned short* __restrict__ csr,
              const float* __restrict__ dinv, const float* __restrict__ b2,
              const float* __restrict__ Wo, const float* __restrict__ bo,
              float* __restrict__ out, int N) {
    __shared__ float Wos[2048];
    __shared__ float b2s[32];
    __shared__ float bos[64];
    int tid = threadIdx.x;
    for (int j = tid; j < 512; j += 256)
        reinterpret_cast<float4*>(Wos)[j] = reinterpret_cast<const float4*>(Wo)[j];
    if (tid < 32) b2s[tid] = b2[tid];
    if (tid < 64) bos[tid] = bo[tid];
    __syncthreads();
    int lane = tid & 63;
    int node = blockIdx.x * 4 + (tid >> 6);
    if (node >= N) return;
    int j = lane >> 3, q = lane & 7;
    int beg = rowbeg[node];
    int end = rowend[node];
    float4 acc = make_float4(0.f, 0.f, 0.f, 0.f);
    for (int base = beg; base < end; base += 64) {
        int idx = base + lane;
        int cv = (idx < end) ? (int)csr[idx] : 0;
        int nin = end - base; if (nin > 64) nin = 64;
        for (int c = 0; c < nin; c += 8) {
            int s = __shfl(cv, c + j, 64);
            if (c + j < nin) {
                const float4 v = *reinterpret_cast<const float4*>(hp + (size_t)s * 32 + q * 4);
                acc.x += v.x; acc.y += v.y; acc.z += v.z; acc.w += v.w;
            }
        }
    }
    #pragma unroll
    for (int d = 8; d < 64; d <<= 1) {
        acc.x += __shfl_xor(acc.x, d, 64);
        acc.y += __shfl_xor(acc.y, d, 64);
        acc.z += __shfl_xor(acc.z, d, 64);
        acc.w += __shfl_xor(acc.w, d, 64);
    }
    float dd = dinv[node];
    float o = bos[lane];
    #pragma unroll
    for (int qq = 0; qq < 8; ++qq) {
        float t0 = __shfl(acc.x, qq, 64);
        float t1 = __shfl(acc.y, qq, 64);
        float t2 = __shfl(acc.z, qq, 64);
        float t3 = __shfl(acc.w, qq, 64);
        float y0 = fmaxf(t0 * dd + b2s[qq*4+0], 0.f);
        float y1 = fmaxf(t1 * dd + b2s[qq*4+1], 0.f);
        float y2 = fmaxf(t2 * dd + b2s[qq*4+2], 0.f);
        float y3 = fmaxf(t3 * dd + b2s[qq*4+3], 0.f);
        o += y0 * Wos[(qq*4+0)*64 + lane];
        o += y1 * Wos[(qq*4+1)*64 + lane];
        o += y2 * Wos[(qq*4+2)*64 + lane];
        o += y3 * Wos[(qq*4+3)*64 + lane];
    }
    out[(size_t)node * 64 + lane] = o;
}

extern "C" void kernel_launch(void* const* d_in, const int* in_sizes, int n_in,
                              void* d_out, int out_size, void* d_ws, size_t ws_size,
                              hipStream_t stream) {
    const float* x  = (const float*)d_in[0];
    const int*   ei = (const int*)d_in[1];
    const float* W1 = (const float*)d_in[2];
    const float* b1 = (const float*)d_in[3];
    const float* W2 = (const float*)d_in[4];
    const float* b2 = (const float*)d_in[5];
    const float* Wo = (const float*)d_in[6];
    const float* bo = (const float*)d_in[7];
    float* out = (float*)d_out;

    const int N = in_sizes[0] / 128;   // 50000
    const int E = in_sizes[1] / 2;     // 1600000
    const int N32 = N * 32;
    const int* src = ei;
    const int* dst = ei + E;

    char* ws = (char*)d_ws;
    size_t off = 0;
    auto alloc = [&](size_t bytes) {
        void* p = ws + off;
        off += (bytes + 255) & ~(size_t)255;
        return p;
    };
    const int nBuckets = (N + 255) >> 8;             // 196
    int*            cursor = (int*)           alloc(256 * 4);
    unsigned int*   binned = (unsigned int*)  alloc((size_t)nBuckets * BCAP * 4);
    int*            rowbeg = (int*)           alloc((size_t)N * 4);
    int*            rowend = (int*)           alloc((size_t)N * 4);
    float*          dinv   = (float*)         alloc((size_t)N * 4);
    unsigned short* csr    = (unsigned short*)alloc((size_t)nBuckets * CCAP * 2);
    float*          bufA   = (float*)         alloc((size_t)N32 * 4);
    float*          bufB   = (float*)         alloc((size_t)N32 * 4);

    const int gRow4  = (N + 3) / 4;                  // 12500
    const int nbinA  = (E + CHUNK - 1) / CHUNK;      // 391
    const int nGemm1 = (N + 511) / 512;              // 98

    hipMemsetAsync(cursor, 0, 256 * 4, stream);
    k_mega1<<<nbinA + nGemm1, 256, 0, stream>>>(src, dst, E, cursor, binned,
                                                x, W1, bufA, N, nbinA);
    k_binB<<<nBuckets, 256, 0, stream>>>(binned, cursor, rowbeg, rowend, dinv,
                                         csr, bufA, N);
    k_aggmm1<<<gRow4, THREADS, 0, stream>>>(bufA, rowbeg, rowend, csr, dinv, b1,
                                            W2, bufB, N);
    k_aggout<<<gRow4, THREADS, 0, stream>>>(bufB, rowbeg, rowend, csr, dinv, b2,
                                            Wo, bo, out, N);
}

// Round 9
// 233.889 us; speedup vs baseline: 1.1184x; 1.1184x over previous
//
#include <hip/hip_runtime.h>

#define THREADS 256
#define CHUNK 2048        // edges per binA block
#define BCAP  16384       // per-bucket edge capacity (mean 8163; fixed input, huge slack)
#define CCAP  (BCAP+256)  // csr region capacity (edges + self entries)

// mega1: blocks [0,nbinA) bin edges into bucket regions (2KB LDS);
//        blocks [nbinA,..) compute h = x @ W1 unscaled (chunk-staged, coalesced).
__global__ __launch_bounds__(256)
void k_mega1(const int* __restrict__ src, const int* __restrict__ dst, int E,
             int* __restrict__ cursor, unsigned int* __restrict__ binned,
             const float* __restrict__ x, const float* __restrict__ W,
             float* __restrict__ h, int N, int nbinA) {
    __shared__ int cnt[256];
    __shared__ int gbs[256];
    __shared__ float Wsh[4096];     // 16 KB
    __shared__ float xs[256][17];   // 17.4 KB, pad 17 -> conflict-free column reads
    int tid = threadIdx.x;
    if ((int)blockIdx.x < nbinA) {
        // ---------- binA: rank + reserve + direct scatter into owned runs ----------
        cnt[tid] = 0;
        __syncthreads();
        int base = blockIdx.x * CHUNK;
        unsigned int pk[8];
        int rk[8];
        unsigned int mask = 0;
        #pragma unroll
        for (int i = 0; i < 2; ++i) {
            int e = base + i * 1024 + tid * 4;
            if (e + 3 < E) {
                int4 d4 = *reinterpret_cast<const int4*>(dst + e);
                int4 s4 = *reinterpret_cast<const int4*>(src + e);
                pk[i*4+0] = ((unsigned)d4.x << 16) | (unsigned)s4.x; rk[i*4+0] = atomicAdd(&cnt[d4.x >> 8], 1);
                pk[i*4+1] = ((unsigned)d4.y << 16) | (unsigned)s4.y; rk[i*4+1] = atomicAdd(&cnt[d4.y >> 8], 1);
                pk[i*4+2] = ((unsigned)d4.z << 16) | (unsigned)s4.z; rk[i*4+2] = atomicAdd(&cnt[d4.z >> 8], 1);
                pk[i*4+3] = ((unsigned)d4.w << 16) | (unsigned)s4.w; rk[i*4+3] = atomicAdd(&cnt[d4.w >> 8], 1);
                mask |= 0xFu << (i * 4);
            } else {
                for (int j = 0; j < 4; ++j) {
                    int k = e + j;
                    if (k < E) {
                        int d = dst[k], s = src[k];
                        pk[i*4+j] = ((unsigned)d << 16) | (unsigned)s;
                        rk[i*4+j] = atomicAdd(&cnt[d >> 8], 1);
                        mask |= 1u << (i * 4 + j);
                    }
                }
            }
        }
        __syncthreads();
        int c = cnt[tid];
        gbs[tid] = c ? atomicAdd(&cursor[tid], c) : 0;
        __syncthreads();
        #pragma unroll
        for (int i = 0; i < 8; ++i) {
            if (mask & (1u << i)) {
                int b = pk[i] >> 24;
                binned[(size_t)b * BCAP + gbs[b] + rk[i]] = pk[i];
            }
        }
    } else {
        // ---------- gemm1: 256 rows/block, 1 row/thread, 16-col staged chunks ----------
        int row0 = ((int)blockIdx.x - nbinA) * 256;
        for (int j = tid; j < 1024; j += 256)
            reinterpret_cast<float4*>(Wsh)[j] = reinterpret_cast<const float4*>(W)[j];
        float acc[32];
        #pragma unroll
        for (int q = 0; q < 32; ++q) acc[q] = 0.f;
        const float4 z4 = make_float4(0.f, 0.f, 0.f, 0.f);
        for (int kc = 0; kc < 128; kc += 16) {
            __syncthreads();
            // stage 256 rows x 16 cols, coalesced 64B segments
            #pragma unroll
            for (int i = 0; i < 4; ++i) {
                int j = i * 256 + tid;
                int r = j >> 2, c4 = j & 3;
                int gr = row0 + r;
                float4 vv = (gr < N)
                    ? *reinterpret_cast<const float4*>(x + (size_t)gr * 128 + kc + c4 * 4)
                    : z4;
                xs[r][c4*4+0] = vv.x; xs[r][c4*4+1] = vv.y;
                xs[r][c4*4+2] = vv.z; xs[r][c4*4+3] = vv.w;
            }
            __syncthreads();
            #pragma unroll
            for (int k = 0; k < 16; ++k) {
                float xv = xs[tid][k];
                const float4* wr = reinterpret_cast<const float4*>(Wsh + (kc + k) * 32);
                #pragma unroll
                for (int q = 0; q < 8; ++q) {
                    float4 w = wr[q];
                    acc[q*4+0] += xv * w.x; acc[q*4+1] += xv * w.y;
                    acc[q*4+2] += xv * w.z; acc[q*4+3] += xv * w.w;
                }
            }
        }
        int row = row0 + tid;
        if (row < N) {
            float4* o = reinterpret_cast<float4*>(h + (size_t)row * 32);
            #pragma unroll
            for (int q = 0; q < 8; ++q)
                o[q] = make_float4(acc[q*4], acc[q*4+1], acc[q*4+2], acc[q*4+3]);
        }
    }
}

// binB: per-bucket node counts -> rowbeg/rowend/dinv/csr (self entry first),
// then scale h rows by dinv in place. 512 threads.
__global__ __launch_bounds__(512)
void k_binB(const unsigned int* __restrict__ binned, const int* __restrict__ cursor,
            int* __restrict__ rowbeg, int* __restrict__ rowend, float* __restrict__ dinvg,
            unsigned short* __restrict__ csr, float* __restrict__ h, int N) {
    __shared__ int cnt[256];
    __shared__ int sc[256];
    __shared__ int lcur[256];
    __shared__ float dv[256];
    int tid = threadIdx.x;
    int b = blockIdx.x;
    size_t ebase = (size_t)b * BCAP;
    int ne = cursor[b];
    if (tid < 256) cnt[tid] = 0;
    __syncthreads();
    for (int i = tid; i < ne; i += 512)
        atomicAdd(&cnt[(binned[ebase + i] >> 16) & 255], 1);
    __syncthreads();
    int myc = (tid < 256) ? cnt[tid] : 0;
    if (tid < 256) sc[tid] = myc;
    __syncthreads();
    for (int off = 1; off < 256; off <<= 1) {
        int v = 0;
        if (tid < 256 && tid >= off) v = sc[tid - off];
        __syncthreads();
        if (tid < 256) sc[tid] += v;
        __syncthreads();
    }
    if (tid < 256) {
        int excl = sc[tid] - myc;
        int node = (b << 8) + tid;
        int cbase = b * CCAP;
        int rb = cbase + excl + tid;
        float di = rsqrtf((float)(myc + 1));
        dv[tid] = di;
        if (node < N) {
            rowbeg[node] = rb;
            rowend[node] = rb + 1 + myc;
            dinvg[node] = di;
            csr[rb] = (unsigned short)node;   // self entry first
        }
        lcur[tid] = excl + tid + 1;
    }
    __syncthreads();
    for (int i = tid; i < ne; i += 512) {
        unsigned int v = binned[ebase + i];
        int nl = (v >> 16) & 255;
        int p = atomicAdd(&lcur[nl], 1);
        csr[(size_t)b * CCAP + p] = (unsigned short)(v & 0xFFFFu);
    }
    __syncthreads();
    float4* h4 = reinterpret_cast<float4*>(h);
    size_t h4base = (size_t)(b << 8) * 8;
    for (int j = tid; j < 2048; j += 512) {
        int nl = j >> 3;
        if (((b << 8) + nl) < N) {
            float4 v = h4[h4base + j];
            float d = dv[nl];
            v.x *= d; v.y *= d; v.z *= d; v.w *= d;
            h4[h4base + j] = v;
        }
    }
}

// agg layer1 + bias + relu + gemm2 + dinv pre-scale. No LDS; W2 column per lane in VGPRs.
__global__ __launch_bounds__(THREADS)
void k_aggmm1(const float* __restrict__ hp, const int* __restrict__ rowbeg,
              const int* __restrict__ rowend, const unsigned short* __restrict__ csr,
              const float* __restrict__ dinv, const float* __restrict__ b1,
              const float* __restrict__ W2, float* __restrict__ hp2, int N) {
    int tid = threadIdx.x;
    int lane = tid & 63;
    int node = blockIdx.x * 4 + (tid >> 6);
    int cp = lane & 31;
    float wcol[32];
    #pragma unroll
    for (int k = 0; k < 32; ++k) wcol[k] = W2[k * 32 + cp];
    float4 bv[8];
    #pragma unroll
    for (int i = 0; i < 8; ++i) bv[i] = reinterpret_cast<const float4*>(b1)[i];
    if (node >= N) return;
    int j = lane >> 3, q = lane & 7;
    int beg = rowbeg[node];
    int end = rowend[node];
    float4 acc = make_float4(0.f, 0.f, 0.f, 0.f);
    for (int base = beg; base < end; base += 64) {
        int idx = base + lane;
        int cv = (idx < end) ? (int)csr[idx] : 0;
        int nin = end - base; if (nin > 64) nin = 64;
        for (int c = 0; c < nin; c += 8) {
            int s = __shfl(cv, c + j, 64);
            if (c + j < nin) {
                const float4 v = *reinterpret_cast<const float4*>(hp + (size_t)s * 32 + q * 4);
                acc.x += v.x; acc.y += v.y; acc.z += v.z; acc.w += v.w;
            }
        }
    }
    #pragma unroll
    for (int d = 8; d < 64; d <<= 1) {
        acc.x += __shfl_xor(acc.x, d, 64);
        acc.y += __shfl_xor(acc.y, d, 64);
        acc.z += __shfl_xor(acc.z, d, 64);
        acc.w += __shfl_xor(acc.w, d, 64);
    }
    float dd = dinv[node];
    float o = 0.f;
    #pragma unroll
    for (int qq = 0; qq < 8; ++qq) {
        float t0 = __shfl(acc.x, qq, 64);
        float t1 = __shfl(acc.y, qq, 64);
        float t2 = __shfl(acc.z, qq, 64);
        float t3 = __shfl(acc.w, qq, 64);
        float y0 = fmaxf(t0 * dd + bv[qq].x, 0.f);
        float y1 = fmaxf(t1 * dd + bv[qq].y, 0.f);
        float y2 = fmaxf(t2 * dd + bv[qq].z, 0.f);
        float y3 = fmaxf(t3 * dd + bv[qq].w, 0.f);
        o += y0 * wcol[qq*4+0] + y1 * wcol[qq*4+1]
           + y2 * wcol[qq*4+2] + y3 * wcol[qq*4+3];
    }
    if (lane < 32) hp2[(size_t)node * 32 + cp] = o * dd;
}

// agg layer2 + bias + relu + head. No LDS; Wo column per lane in VGPRs.
__global__ __launch_bounds__(THREADS)
void k_aggout(const float* __restrict__ hp, const int* __restrict__ rowbeg,
              const int* __restrict__ rowend, const unsigned short* __restrict__ csr,
              const float* __restrict__ dinv, const float* __restrict__ b2,
              const float* __restrict__ Wo, const float* __restrict__ bo,
              float* __restrict__ out, int N) {
    int tid = threadIdx.x;
    int lane = tid & 63;
    int node = blockIdx.x * 4 + (tid >> 6);
    float wcol[32];
    #pragma unroll
    for (int k = 0; k < 32; ++k) wcol[k] = Wo[k * 64 + lane];
    float4 bv[8];
    #pragma unroll
    for (int i = 0; i < 8; ++i) bv[i] = reinterpret_cast<const float4*>(b2)[i];
    float obias = bo[lane];
    if (node >= N) return;
    int j = lane >> 3, q = lane & 7;
    int beg = rowbeg[node];
    int end = rowend[node];
    float4 acc = make_float4(0.f, 0.f, 0.f, 0.f);
    for (int base = beg; base < end; base += 64) {
        int idx = base + lane;
        int cv = (idx < end) ? (int)csr[idx] : 0;
        int nin = end - base; if (nin > 64) nin = 64;
        for (int c = 0; c < nin; c += 8) {
            int s = __shfl(cv, c + j, 64);
            if (c + j < nin) {
                const float4 v = *reinterpret_cast<const float4*>(hp + (size_t)s * 32 + q * 4);
                acc.x += v.x; acc.y += v.y; acc.z += v.z; acc.w += v.w;
            }
        }
    }
    #pragma unroll
    for (int d = 8; d < 64; d <<= 1) {
        acc.x += __shfl_xor(acc.x, d, 64);
        acc.y += __shfl_xor(acc.y, d, 64);
        acc.z += __shfl_xor(acc.z, d, 64);
        acc.w += __shfl_xor(acc.w, d, 64);
    }
    float dd = dinv[node];
    float o = obias;
    #pragma unroll
    for (int qq = 0; qq < 8; ++qq) {
        float t0 = __shfl(acc.x, qq, 64);
        float t1 = __shfl(acc.y, qq, 64);
        float t2 = __shfl(acc.z, qq, 64);
        float t3 = __shfl(acc.w, qq, 64);
        float y0 = fmaxf(t0 * dd + bv[qq].x, 0.f);
        float y1 = fmaxf(t1 * dd + bv[qq].y, 0.f);
        float y2 = fmaxf(t2 * dd + bv[qq].z, 0.f);
        float y3 = fmaxf(t3 * dd + bv[qq].w, 0.f);
        o += y0 * wcol[qq*4+0] + y1 * wcol[qq*4+1]
           + y2 * wcol[qq*4+2] + y3 * wcol[qq*4+3];
    }
    out[(size_t)node * 64 + lane] = o;
}

extern "C" void kernel_launch(void* const* d_in, const int* in_sizes, int n_in,
                              void* d_out, int out_size, void* d_ws, size_t ws_size,
                              hipStream_t stream) {
    const float* x  = (const float*)d_in[0];
    const int*   ei = (const int*)d_in[1];
    const float* W1 = (const float*)d_in[2];
    const float* b1 = (const float*)d_in[3];
    const float* W2 = (const float*)d_in[4];
    const float* b2 = (const float*)d_in[5];
    const float* Wo = (const float*)d_in[6];
    const float* bo = (const float*)d_in[7];
    float* out = (float*)d_out;

    const int N = in_sizes[0] / 128;   // 50000
    const int E = in_sizes[1] / 2;     // 1600000
    const int N32 = N * 32;
    const int* src = ei;
    const int* dst = ei + E;

    char* ws = (char*)d_ws;
    size_t off = 0;
    auto alloc = [&](size_t bytes) {
        void* p = ws + off;
        off += (bytes + 255) & ~(size_t)255;
        return p;
    };
    const int nBuckets = (N + 255) >> 8;             // 196
    int*            cursor = (int*)           alloc(256 * 4);
    unsigned int*   binned = (unsigned int*)  alloc((size_t)nBuckets * BCAP * 4);
    int*            rowbeg = (int*)           alloc((size_t)N * 4);
    int*            rowend = (int*)           alloc((size_t)N * 4);
    float*          dinv   = (float*)         alloc((size_t)N * 4);
    unsigned short* csr    = (unsigned short*)alloc((size_t)nBuckets * CCAP * 2);
    float*          bufA   = (float*)         alloc((size_t)N32 * 4);
    float*          bufB   = (float*)         alloc((size_t)N32 * 4);

    const int gRow4  = (N + 3) / 4;                  // 12500
    const int nbinA  = (E + CHUNK - 1) / CHUNK;      // 782
    const int nGemm1 = (N + 255) / 256;              // 196

    hipMemsetAsync(cursor, 0, 256 * 4, stream);
    k_mega1<<<nbinA + nGemm1, 256, 0, stream>>>(src, dst, E, cursor, binned,
                                                x, W1, bufA, N, nbinA);
    k_binB<<<nBuckets, 512, 0, stream>>>(binned, cursor, rowbeg, rowend, dinv,
                                         csr, bufA, N);
    k_aggmm1<<<gRow4, THREADS, 0, stream>>>(bufA, rowbeg, rowend, csr, dinv, b1,
                                            W2, bufB, N);
    k_aggout<<<gRow4, THREADS, 0, stream>>>(bufB, rowbeg, rowend, csr, dinv, b2,
                                            Wo, bo, out, N);
}

// Round 10
// 219.196 us; speedup vs baseline: 1.1933x; 1.0670x over previous
//
#include <hip/hip_runtime.h>

#define THREADS 256
#define CHUNK 4096        // edges per binA block
#define BCAP  16384       // per-bucket edge capacity (mean 8163; fixed input, huge slack)
#define CCAP  (BCAP+4608) // csr region capacity (edges + self + per-row pad to x16)

// mega1: blocks [0,nGemm) compute h = x @ W1 unscaled (W via scalar loads, xs staged);
//        blocks [nGemm,..) bin edges into bucket-owned regions (2KB LDS).
__global__ __launch_bounds__(256)
void k_mega1(const int* __restrict__ src, const int* __restrict__ dst, int E,
             int* __restrict__ cursor, unsigned int* __restrict__ binned,
             const float* __restrict__ x, const float* __restrict__ W,
             float* __restrict__ h, int N, int nGemm) {
    __shared__ int cnt[256];
    __shared__ int gbs[256];
    __shared__ float xs[256][17];   // 17.4 KB, pad 17 -> conflict-free column reads
    int tid = threadIdx.x;
    if ((int)blockIdx.x >= nGemm) {
        // ---------- binA: rank + reserve + direct scatter into owned runs ----------
        cnt[tid] = 0;
        __syncthreads();
        int base = ((int)blockIdx.x - nGemm) * CHUNK;
        unsigned int pk[16];
        int rk[16];
        unsigned int mask = 0;
        #pragma unroll
        for (int i = 0; i < 4; ++i) {
            int e = base + i * 1024 + tid * 4;
            if (e + 3 < E) {
                int4 d4 = *reinterpret_cast<const int4*>(dst + e);
                int4 s4 = *reinterpret_cast<const int4*>(src + e);
                pk[i*4+0] = ((unsigned)d4.x << 16) | (unsigned)s4.x; rk[i*4+0] = atomicAdd(&cnt[d4.x >> 8], 1);
                pk[i*4+1] = ((unsigned)d4.y << 16) | (unsigned)s4.y; rk[i*4+1] = atomicAdd(&cnt[d4.y >> 8], 1);
                pk[i*4+2] = ((unsigned)d4.z << 16) | (unsigned)s4.z; rk[i*4+2] = atomicAdd(&cnt[d4.z >> 8], 1);
                pk[i*4+3] = ((unsigned)d4.w << 16) | (unsigned)s4.w; rk[i*4+3] = atomicAdd(&cnt[d4.w >> 8], 1);
                mask |= 0xFu << (i * 4);
            } else {
                for (int j = 0; j < 4; ++j) {
                    int k = e + j;
                    if (k < E) {
                        int d = dst[k], s = src[k];
                        pk[i*4+j] = ((unsigned)d << 16) | (unsigned)s;
                        rk[i*4+j] = atomicAdd(&cnt[d >> 8], 1);
                        mask |= 1u << (i * 4 + j);
                    }
                }
            }
        }
        __syncthreads();
        int c = cnt[tid];
        gbs[tid] = c ? atomicAdd(&cursor[tid], c) : 0;
        __syncthreads();
        #pragma unroll
        for (int i = 0; i < 16; ++i) {
            if (mask & (1u << i)) {
                int b = pk[i] >> 24;
                binned[(size_t)b * BCAP + gbs[b] + rk[i]] = pk[i];
            }
        }
    } else {
        // ---------- gemm1: 256 rows/block; W read wave-uniform (scalar loads) ----------
        int row0 = (int)blockIdx.x * 256;
        float acc[32];
        #pragma unroll
        for (int q = 0; q < 32; ++q) acc[q] = 0.f;
        const float4 z4 = make_float4(0.f, 0.f, 0.f, 0.f);
        for (int kc = 0; kc < 128; kc += 16) {
            __syncthreads();
            #pragma unroll
            for (int i = 0; i < 4; ++i) {
                int j = i * 256 + tid;
                int r = j >> 2, c4 = j & 3;
                int gr = row0 + r;
                float4 vv = (gr < N)
                    ? *reinterpret_cast<const float4*>(x + (size_t)gr * 128 + kc + c4 * 4)
                    : z4;
                xs[r][c4*4+0] = vv.x; xs[r][c4*4+1] = vv.y;
                xs[r][c4*4+2] = vv.z; xs[r][c4*4+3] = vv.w;
            }
            __syncthreads();
            #pragma unroll
            for (int k = 0; k < 16; ++k) {
                float xv = xs[tid][k];
                const float4* wr = reinterpret_cast<const float4*>(W + (kc + k) * 32);
                #pragma unroll
                for (int q = 0; q < 8; ++q) {
                    float4 w = wr[q];   // wave-uniform address -> scalar load
                    acc[q*4+0] += xv * w.x; acc[q*4+1] += xv * w.y;
                    acc[q*4+2] += xv * w.z; acc[q*4+3] += xv * w.w;
                }
            }
        }
        int row = row0 + tid;
        if (row < N) {
            float4* o = reinterpret_cast<float4*>(h + (size_t)row * 32);
            #pragma unroll
            for (int q = 0; q < 8; ++q)
                o[q] = make_float4(acc[q*4], acc[q*4+1], acc[q*4+2], acc[q*4+3]);
        } else if (row == N) {   // dummy pad row: zeros
            float4* o = reinterpret_cast<float4*>(h + (size_t)N * 32);
            #pragma unroll
            for (int q = 0; q < 8; ++q) o[q] = z4;
        }
    }
}

// binB: per-bucket node counts -> rowbeg/rowend (padded to x16)/dinv/csr
// (self entry first, pad entries = N), then scale h rows by dinv in place.
__global__ __launch_bounds__(512)
void k_binB(const unsigned int* __restrict__ binned, const int* __restrict__ cursor,
            int* __restrict__ rowbeg, int* __restrict__ rowend, float* __restrict__ dinvg,
            unsigned short* __restrict__ csr, float* __restrict__ h, int N) {
    __shared__ int cnt[256];
    __shared__ int sc[256];
    __shared__ int lcur[256];
    __shared__ float dv[256];
    int tid = threadIdx.x;
    int b = blockIdx.x;
    size_t ebase = (size_t)b * BCAP;
    int ne = cursor[b];
    if (tid < 256) cnt[tid] = 0;
    __syncthreads();
    for (int i = tid; i < ne; i += 512)
        atomicAdd(&cnt[(binned[ebase + i] >> 16) & 255], 1);
    __syncthreads();
    int myc = 0, pcnt = 0;
    if (tid < 256) {
        myc = cnt[tid];
        pcnt = (myc + 1 + 15) & ~15;   // self + edges, padded to x16
        sc[tid] = pcnt;
    }
    __syncthreads();
    for (int off = 1; off < 256; off <<= 1) {
        int v = 0;
        if (tid < 256 && tid >= off) v = sc[tid - off];
        __syncthreads();
        if (tid < 256) sc[tid] += v;
        __syncthreads();
    }
    int pexcl = 0;
    int cbase = b * CCAP;
    if (tid < 256) {
        pexcl = sc[tid] - pcnt;
        int node = (b << 8) + tid;
        int rb = cbase + pexcl;
        float di = rsqrtf((float)(myc + 1));
        dv[tid] = di;
        if (node < N) {
            rowbeg[node] = rb;
            rowend[node] = rb + pcnt;
            dinvg[node] = di;
            csr[rb] = (unsigned short)node;   // self entry first
        }
        lcur[tid] = pexcl + 1;
    }
    __syncthreads();
    for (int i = tid; i < ne; i += 512) {
        unsigned int v = binned[ebase + i];
        int nl = (v >> 16) & 255;
        int p = atomicAdd(&lcur[nl], 1);
        csr[cbase + p] = (unsigned short)(v & 0xFFFFu);
    }
    __syncthreads();
    if (tid < 256) {   // fill pad slots with dummy node N (zero row)
        for (int p = pexcl + 1 + myc; p < pexcl + pcnt; ++p)
            csr[cbase + p] = (unsigned short)N;
    }
    __syncthreads();
    float4* h4 = reinterpret_cast<float4*>(h);
    size_t h4base = (size_t)(b << 8) * 8;
    for (int j = tid; j < 2048; j += 512) {
        int nl = j >> 3;
        if (((b << 8) + nl) < N) {
            float4 v = h4[h4base + j];
            float d = dv[nl];
            v.x *= d; v.y *= d; v.z *= d; v.w *= d;
            h4[h4base + j] = v;
        }
    }
}

// agg layer1 + bias + relu + gemm2 + dinv pre-scale. Rows padded to x16:
// 2x8-unrolled gather, two loads in flight, no remainder logic.
__global__ __launch_bounds__(THREADS)
void k_aggmm1(const float* __restrict__ hp, const int* __restrict__ rowbeg,
              const int* __restrict__ rowend, const unsigned short* __restrict__ csr,
              const float* __restrict__ dinv, const float* __restrict__ b1,
              const float* __restrict__ W2, float* __restrict__ hp2, int N) {
    int tid = threadIdx.x;
    int lane = tid & 63;
    int node = blockIdx.x * 4 + (tid >> 6);
    if (node > N) return;
    int cp = lane & 31;
    if (node == N) {   // dummy pad row of hp2: zeros
        if (lane < 8) reinterpret_cast<float4*>(hp2 + (size_t)N * 32)[lane] =
            make_float4(0.f, 0.f, 0.f, 0.f);
        return;
    }
    float wcol[32];
    #pragma unroll
    for (int k = 0; k < 32; ++k) wcol[k] = W2[k * 32 + cp];
    float4 bv[8];
    #pragma unroll
    for (int i = 0; i < 8; ++i) bv[i] = reinterpret_cast<const float4*>(b1)[i];
    int j = lane >> 3, q = lane & 7;
    int beg = rowbeg[node];
    int end = rowend[node];
    float4 acc = make_float4(0.f, 0.f, 0.f, 0.f);
    float4 acc2 = make_float4(0.f, 0.f, 0.f, 0.f);
    const float4* hp4 = reinterpret_cast<const float4*>(hp);
    for (int base = beg; base < end; base += 64) {
        int idx = base + lane;
        int cv = (idx < end) ? (int)csr[idx] : 0;
        int nin = end - base; if (nin > 64) nin = 64;   // multiple of 16
        for (int c = 0; c < nin; c += 16) {
            int s0 = __shfl(cv, c + j, 64);
            int s1 = __shfl(cv, c + 8 + j, 64);
            float4 v0 = hp4[(size_t)s0 * 8 + q];
            float4 v1 = hp4[(size_t)s1 * 8 + q];
            acc.x += v0.x; acc.y += v0.y; acc.z += v0.z; acc.w += v0.w;
            acc2.x += v1.x; acc2.y += v1.y; acc2.z += v1.z; acc2.w += v1.w;
        }
    }
    acc.x += acc2.x; acc.y += acc2.y; acc.z += acc2.z; acc.w += acc2.w;
    #pragma unroll
    for (int d = 8; d < 64; d <<= 1) {
        acc.x += __shfl_xor(acc.x, d, 64);
        acc.y += __shfl_xor(acc.y, d, 64);
        acc.z += __shfl_xor(acc.z, d, 64);
        acc.w += __shfl_xor(acc.w, d, 64);
    }
    float dd = dinv[node];
    float o = 0.f;
    #pragma unroll
    for (int qq = 0; qq < 8; ++qq) {
        float t0 = __shfl(acc.x, qq, 64);
        float t1 = __shfl(acc.y, qq, 64);
        float t2 = __shfl(acc.z, qq, 64);
        float t3 = __shfl(acc.w, qq, 64);
        float y0 = fmaxf(t0 * dd + bv[qq].x, 0.f);
        float y1 = fmaxf(t1 * dd + bv[qq].y, 0.f);
        float y2 = fmaxf(t2 * dd + bv[qq].z, 0.f);
        float y3 = fmaxf(t3 * dd + bv[qq].w, 0.f);
        o += y0 * wcol[qq*4+0] + y1 * wcol[qq*4+1]
           + y2 * wcol[qq*4+2] + y3 * wcol[qq*4+3];
    }
    if (lane < 32) hp2[(size_t)node * 32 + cp] = o * dd;
}

// agg layer2 + bias + relu + head.
__global__ __launch_bounds__(THREADS)
void k_aggout(const float* __restrict__ hp, const int* __restrict__ rowbeg,
              const int* __restrict__ rowend, const unsigned short* __restrict__ csr,
              const float* __restrict__ dinv, const float* __restrict__ b2,
              const float* __restrict__ Wo, const float* __restrict__ bo,
              float* __restrict__ out, int N) {
    int tid = threadIdx.x;
    int lane = tid & 63;
    int node = blockIdx.x * 4 + (tid >> 6);
    if (node >= N) return;
    float wcol[32];
    #pragma unroll
    for (int k = 0; k < 32; ++k) wcol[k] = Wo[k * 64 + lane];
    float4 bv[8];
    #pragma unroll
    for (int i = 0; i < 8; ++i) bv[i] = reinterpret_cast<const float4*>(b2)[i];
    float obias = bo[lane];
    int j = lane >> 3, q = lane & 7;
    int beg = rowbeg[node];
    int end = rowend[node];
    float4 acc = make_float4(0.f, 0.f, 0.f, 0.f);
    float4 acc2 = make_float4(0.f, 0.f, 0.f, 0.f);
    const float4* hp4 = reinterpret_cast<const float4*>(hp);
    for (int base = beg; base < end; base += 64) {
        int idx = base + lane;
        int cv = (idx < end) ? (int)csr[idx] : 0;
        int nin = end - base; if (nin > 64) nin = 64;
        for (int c = 0; c < nin; c += 16) {
            int s0 = __shfl(cv, c + j, 64);
            int s1 = __shfl(cv, c + 8 + j, 64);
            float4 v0 = hp4[(size_t)s0 * 8 + q];
            float4 v1 = hp4[(size_t)s1 * 8 + q];
            acc.x += v0.x; acc.y += v0.y; acc.z += v0.z; acc.w += v0.w;
            acc2.x += v1.x; acc2.y += v1.y; acc2.z += v1.z; acc2.w += v1.w;
        }
    }
    acc.x += acc2.x; acc.y += acc2.y; acc.z += acc2.z; acc.w += acc2.w;
    #pragma unroll
    for (int d = 8; d < 64; d <<= 1) {
        acc.x += __shfl_xor(acc.x, d, 64);
        acc.y += __shfl_xor(acc.y, d, 64);
        acc.z += __shfl_xor(acc.z, d, 64);
        acc.w += __shfl_xor(acc.w, d, 64);
    }
    float dd = dinv[node];
    float o = obias;
    #pragma unroll
    for (int qq = 0; qq < 8; ++qq) {
        float t0 = __shfl(acc.x, qq, 64);
        float t1 = __shfl(acc.y, qq, 64);
        float t2 = __shfl(acc.z, qq, 64);
        float t3 = __shfl(acc.w, qq, 64);
        float y0 = fmaxf(t0 * dd + bv[qq].x, 0.f);
        float y1 = fmaxf(t1 * dd + bv[qq].y, 0.f);
        float y2 = fmaxf(t2 * dd + bv[qq].z, 0.f);
        float y3 = fmaxf(t3 * dd + bv[qq].w, 0.f);
        o += y0 * wcol[qq*4+0] + y1 * wcol[qq*4+1]
           + y2 * wcol[qq*4+2] + y3 * wcol[qq*4+3];
    }
    out[(size_t)node * 64 + lane] = o;
}

extern "C" void kernel_launch(void* const* d_in, const int* in_sizes, int n_in,
                              void* d_out, int out_size, void* d_ws, size_t ws_size,
                              hipStream_t stream) {
    const float* x  = (const float*)d_in[0];
    const int*   ei = (const int*)d_in[1];
    const float* W1 = (const float*)d_in[2];
    const float* b1 = (const float*)d_in[3];
    const float* W2 = (const float*)d_in[4];
    const float* b2 = (const float*)d_in[5];
    const float* Wo = (const float*)d_in[6];
    const float* bo = (const float*)d_in[7];
    float* out = (float*)d_out;

    const int N = in_sizes[0] / 128;   // 50000
    const int E = in_sizes[1] / 2;     // 1600000
    const int* src = ei;
    const int* dst = ei + E;

    char* ws = (char*)d_ws;
    size_t off = 0;
    auto alloc = [&](size_t bytes) {
        void* p = ws + off;
        off += (bytes + 255) & ~(size_t)255;
        return p;
    };
    const int nBuckets = (N + 255) >> 8;             // 196
    int*            cursor = (int*)           alloc(256 * 4);
    unsigned int*   binned = (unsigned int*)  alloc((size_t)nBuckets * BCAP * 4);
    int*            rowbeg = (int*)           alloc((size_t)N * 4);
    int*            rowend = (int*)           alloc((size_t)N * 4);
    float*          dinv   = (float*)         alloc((size_t)N * 4);
    unsigned short* csr    = (unsigned short*)alloc((size_t)nBuckets * CCAP * 2);
    float*          bufA   = (float*)         alloc((size_t)(N + 1) * 32 * 4);
    float*          bufB   = (float*)         alloc((size_t)(N + 1) * 32 * 4);

    const int nbinA  = (E + CHUNK - 1) / CHUNK;      // 391
    const int nGemm1 = (N + 256) / 256;              // 196 (covers row N)
    const int gAgg1  = (N + 1 + 3) / 4;              // covers node N (zero row)
    const int gAgg2  = (N + 3) / 4;

    hipMemsetAsync(cursor, 0, 256 * 4, stream);
    k_mega1<<<nGemm1 + nbinA, 256, 0, stream>>>(src, dst, E, cursor, binned,
                                                x, W1, bufA, N, nGemm1);
    k_binB<<<nBuckets, 512, 0, stream>>>(binned, cursor, rowbeg, rowend, dinv,
                                         csr, bufA, N);
    k_aggmm1<<<gAgg1, THREADS, 0, stream>>>(bufA, rowbeg, rowend, csr, dinv, b1,
                                            W2, bufB, N);
    k_aggout<<<gAgg2, THREADS, 0, stream>>>(bufB, rowbeg, rowend, csr, dinv, b2,
                                            Wo, bo, out, N);
}